// Round 17
// baseline (1012.809 us; speedup 1.0000x reference)
//
#include <hip/hip_runtime.h>

typedef short s16x8 __attribute__((ext_vector_type(8)));
typedef float f32x4 __attribute__((ext_vector_type(4)));

#define NB    128
#define NTOK  996
#define NPAD  1024
#define NGRP  4
#define GSZ   256
#define NLAY  8

__device__ __forceinline__ float bf2f(unsigned short u){
    unsigned int v = ((unsigned int)u) << 16;
    return __uint_as_float(v);
}
__device__ __forceinline__ unsigned short f2bf(float f){
    unsigned int x = __float_as_uint(f);
    unsigned int r = (x + 0x7fffu + ((x >> 16) & 1u)) >> 16;
    return (unsigned short)r;
}
__device__ __forceinline__ unsigned int packbf(float a, float b){
    return (unsigned int)f2bf(a) | ((unsigned int)f2bf(b) << 16);
}
__device__ __forceinline__ float silu(float v){
    return v / (1.0f + __expf(-v));
}

// derive one MFMA A/B fragment (8 dims at d0) of gamma*qk+beta with rotary
__device__ __forceinline__ s16x8 derive_core(const unsigned short* __restrict__ qrow, int d0,
        float4 g0, float4 g1, float4 b0, float4 b1,
        const float* __restrict__ rp, bool rot){
    uint4 u = *(const uint4*)(qrow + d0);
    float y0 = bf2f((unsigned short)(u.x & 0xffffu))*g0.x + b0.x;
    float y1 = bf2f((unsigned short)(u.x >> 16))    *g0.y + b0.y;
    float y2 = bf2f((unsigned short)(u.y & 0xffffu))*g0.z + b0.z;
    float y3 = bf2f((unsigned short)(u.y >> 16))    *g0.w + b0.w;
    float y4 = bf2f((unsigned short)(u.z & 0xffffu))*g1.x + b1.x;
    float y5 = bf2f((unsigned short)(u.z >> 16))    *g1.y + b1.y;
    float y6 = bf2f((unsigned short)(u.w & 0xffffu))*g1.z + b1.z;
    float y7 = bf2f((unsigned short)(u.w >> 16))    *g1.w + b1.w;
    if (rot){
        float4 c4 = *(const float4*)(rp);
        float4 s4 = *(const float4*)(rp + 16);
        float a;
        a = y0; y0 = a*c4.x - y1*s4.x; y1 = y1*c4.x + a*s4.x;
        a = y2; y2 = a*c4.y - y3*s4.y; y3 = y3*c4.y + a*s4.y;
        a = y4; y4 = a*c4.z - y5*s4.z; y5 = y5*c4.z + a*s4.z;
        a = y6; y6 = a*c4.w - y7*s4.w; y7 = y7*c4.w + a*s4.w;
    }
    union { unsigned int uu[4]; s16x8 s; } r;
    r.uu[0] = packbf(y0, y1);
    r.uu[1] = packbf(y2, y3);
    r.uu[2] = packbf(y4, y5);
    r.uu[3] = packbf(y6, y7);
    return r.s;
}

// ---------------- embed + positional (+ rope table) ----------------
__global__ __launch_bounds__(256) void k_embed(const int* __restrict__ kmer,
                                               const float* __restrict__ emb,
                                               const float* __restrict__ ps,
                                               float* __restrict__ x,
                                               float* __restrict__ rope){
    int gid = blockIdx.x * 256 + threadIdx.x;
    if (gid < NPAD){
        float tf2 = (float)gid;
        #pragma unroll
        for (int i = 0; i < 16; i++){
            float inv = expf(((float)(2*i) / 32.0f) * -9.210340371976184f);
            float ang = tf2 * inv;
            rope[gid*32 + i]      = cosf(ang);
            rope[gid*32 + 16 + i] = sinf(ang);
        }
    }
    if (gid >= NB * NTOK) return;
    int b = gid / NTOK;
    int tt = gid - b * NTOK;
    int idx = kmer[gid];
    const float* er = emb + (size_t)idx * 16;
    float pscale = ps[0];
    float tf = (float)tt;
    float* xr = x + (size_t)gid * 16;
    #pragma unroll
    for (int i = 0; i < 8; i++){
        float inv = expf(((float)(2*i) / 16.0f) * -9.210340371976184f);
        float ang = tf * inv;
        xr[i]     = er[i]     + sinf(ang) * pscale;
        xr[8 + i] = er[8 + i] + cosf(ang) * pscale;
    }
}

// ---------------- per-layer tokenwise + fused lin_kv partial ----------------
// block = (b, qt): 256 padded tokens. Single-buffered chunk arena (42.5 KB LDS).
__global__ __launch_bounds__(256, 2) void k_pre(const float* __restrict__ x,
                                             const float* __restrict__ Wh, const float* __restrict__ bh,
                                             const float* __restrict__ Wqk, const float* __restrict__ bqk,
                                             const float* __restrict__ norm_g,
                                             const float* __restrict__ gamma, const float* __restrict__ beta,
                                             const float* __restrict__ rope, int layer,
                                             unsigned short* __restrict__ qk,
                                             unsigned short* __restrict__ vT,
                                             unsigned short* __restrict__ gateb,
                                             float* __restrict__ linkvp){
    __shared__ __align__(16) unsigned short WcT[192 * 40]; // [col][dim0..15,16=bias,pad0]
    __shared__ unsigned int nrm[256][4];                   // own packed normed dims 0..7
    __shared__ __align__(16) unsigned char arena[23040];   // LkT 18432 + Vt 4608; As aliases [0,20480)
    unsigned short* As = (unsigned short*)arena;           // [token][40], dead after preload
    unsigned short* LkT = (unsigned short*)arena;
    unsigned short* Vt  = (unsigned short*)(arena + 18432);
    int tid = threadIdx.x;
    int qt = blockIdx.x & 3, b = blockIdx.x >> 2;
    const float* Whl = Wh  + (size_t)layer * 1024;
    const float* Wql = Wqk + (size_t)layer * 2048;
    const float* gLin = gamma + (size_t)layer * 512 + 384;
    const float* bLin = beta  + (size_t)layer * 512 + 384;
    for (int i = tid; i < 1024; i += 256){ int d = i >> 6, c = i & 63;  WcT[c*40 + d] = f2bf(Whl[i]); }
    for (int i = tid; i < 2048; i += 256){ int d = i >> 7, c = i & 127; WcT[(64 + c)*40 + d] = f2bf(Wql[i]); }
    if (tid < 192){
        int i = tid;
        float bv = (i < 64) ? bh[layer*64 + i] : bqk[layer*128 + (i - 64)];
        WcT[i*40 + 16] = f2bf(bv);
        WcT[i*40 + 17] = 0;
        unsigned int* zz = (unsigned int*)(WcT + i*40 + 18);
        #pragma unroll
        for (int k = 0; k < 7; k++) zz[k] = 0u;
    }
    int tt = qt*256 + tid;
    int tsafe = tt < NTOK ? tt : (NTOK - 1);
    float g = norm_g[layer];
    unsigned int* dd = (unsigned int*)(As + tid * 40);
    {
        const float4* xr4 = (const float4*)(x + ((size_t)b*NTOK + tsafe) * 16);
        float cur[16];
        float s2 = 0.f;
        #pragma unroll
        for (int c = 0; c < 4; c++){
            float4 v4 = xr4[c];
            cur[4*c] = v4.x; cur[4*c+1] = v4.y; cur[4*c+2] = v4.z; cur[4*c+3] = v4.w;
        }
        #pragma unroll
        for (int d = 0; d < 16; d++) s2 += cur[d]*cur[d];
        float sc = g / fmaxf(sqrtf(s2) * 0.25f, 1e-5f);
        #pragma unroll
        for (int i = 0; i < 4; i++) nrm[tid][i] = packbf(cur[2*i]*sc, cur[2*i+1]*sc);
        #pragma unroll
        for (int i = 0; i < 4; i++) dd[4 + i] = packbf(cur[8 + 2*i]*sc, cur[9 + 2*i]*sc);
        dd[8] = 0x00003f80u; // dim16 = 1.0 (bias lane)
        #pragma unroll
        for (int i = 9; i < 16; i++) dd[i] = 0u;
    }
    __syncthreads();
    if (tt == 0){
        #pragma unroll
        for (int i = 0; i < 4; i++) dd[i] = 0u;
    } else if (tid > 0){
        #pragma unroll
        for (int i = 0; i < 4; i++) dd[i] = nrm[tid - 1][i];
    } else {
        const float4* xp4 = (const float4*)(x + ((size_t)b*NTOK + tt - 1) * 16);
        float prv[16]; float p2 = 0.f;
        #pragma unroll
        for (int c = 0; c < 4; c++){
            float4 v4 = xp4[c];
            prv[4*c] = v4.x; prv[4*c+1] = v4.y; prv[4*c+2] = v4.z; prv[4*c+3] = v4.w;
        }
        #pragma unroll
        for (int d = 0; d < 16; d++) p2 += prv[d]*prv[d];
        float sp = g / fmaxf(sqrtf(p2) * 0.25f, 1e-5f);
        #pragma unroll
        for (int i = 0; i < 4; i++) dd[i] = packbf(prv[2*i]*sp, prv[2*i+1]*sp);
    }
    __syncthreads();
    int w = tid >> 6, lane = tid & 63, m16 = lane & 15, quad = lane >> 4;
    s16x8 wf[12];
    #pragma unroll
    for (int mi = 0; mi < 12; mi++)
        wf[mi] = *(const s16x8*)(WcT + (mi*16 + m16)*40 + quad*8);
    s16x8 bfr[4];
    #pragma unroll
    for (int nt = 0; nt < 4; nt++)
        bfr[nt] = *(const s16x8*)(As + ((w*64 + nt*16 + m16))*40 + quad*8);
    __syncthreads();   // preloads done; arena reusable
    f32x4 zacc = {0.f,0.f,0.f,0.f};
    f32x4 lacc[2][2] = {{{0,0,0,0},{0,0,0,0}},{{0,0,0,0},{0,0,0,0}}};
    #pragma unroll
    for (int nt = 0; nt < 4; nt++){
        int tloc = w*64 + nt*16 + m16;
        int ttk = qt*256 + tloc;           // within-batch token (may be pad)
        bool tv = ttk < NTOK;
        int c = w*16 + m16;                // column in chunk staging
        size_t rowq = ((size_t)b*NPAD + ttk);
        #pragma unroll
        for (int mi = 0; mi < 12; mi++){
            f32x4 r = __builtin_amdgcn_mfma_f32_16x16x32_bf16(wf[mi], bfr[nt], zacc, 0, 0, 0);
            float sv[4];
            #pragma unroll
            for (int reg = 0; reg < 4; reg++) sv[reg] = silu(r[reg]);
            int wc0 = mi*16 + quad*4;
            if (mi < 2){
                #pragma unroll
                for (int reg = 0; reg < 4; reg++){
                    unsigned short pv = tv ? f2bf(sv[reg]) : (unsigned short)0;
                    vT[((size_t)b*32 + wc0 + reg)*NPAD + ttk] = pv;
                    Vt[(wc0 + reg)*72 + c] = pv;
                }
            } else if (mi < 4){
                *(uint2*)(gateb + rowq*32 + (wc0 - 32)) = make_uint2(packbf(sv[0],sv[1]), packbf(sv[2],sv[3]));
            } else {
                int qd = wc0 - 64;
                *(uint2*)(qk + rowq*128 + qd) = make_uint2(packbf(sv[0],sv[1]), packbf(sv[2],sv[3]));
                float y0 = sv[0]*gLin[qd]   + bLin[qd];
                float y1 = sv[1]*gLin[qd+1] + bLin[qd+1];
                float y2 = sv[2]*gLin[qd+2] + bLin[qd+2];
                float y3 = sv[3]*gLin[qd+3] + bLin[qd+3];
                if (qd < 32){
                    const float* rp = rope + ttk*32 + (qd >> 1);
                    float c0 = rp[0], s0 = rp[16], c1 = rp[1], s1 = rp[17];
                    float a;
                    a = y0; y0 = a*c0 - y1*s0; y1 = y1*c0 + a*s0;
                    a = y2; y2 = a*c1 - y3*s1; y3 = y3*c1 + a*s1;
                }
                LkT[(qd+0)*72 + c] = f2bf(y0);
                LkT[(qd+1)*72 + c] = f2bf(y1);
                LkT[(qd+2)*72 + c] = f2bf(y2);
                LkT[(qd+3)*72 + c] = f2bf(y3);
            }
        }
        __syncthreads();   // LkT/Vt chunk ready
        #pragma unroll
        for (int ks2 = 0; ks2 < 2; ks2++){
            s16x8 a0 = *(const s16x8*)(LkT + ((2*w  )*16 + m16)*72 + ks2*32 + quad*8);
            s16x8 a1 = *(const s16x8*)(LkT + ((2*w+1)*16 + m16)*72 + ks2*32 + quad*8);
            s16x8 b0 = *(const s16x8*)(Vt + (m16)*72 + ks2*32 + quad*8);
            s16x8 b1 = *(const s16x8*)(Vt + (16 + m16)*72 + ks2*32 + quad*8);
            lacc[0][0] = __builtin_amdgcn_mfma_f32_16x16x32_bf16(a0, b0, lacc[0][0], 0,0,0);
            lacc[0][1] = __builtin_amdgcn_mfma_f32_16x16x32_bf16(a0, b1, lacc[0][1], 0,0,0);
            lacc[1][0] = __builtin_amdgcn_mfma_f32_16x16x32_bf16(a1, b0, lacc[1][0], 0,0,0);
            lacc[1][1] = __builtin_amdgcn_mfma_f32_16x16x32_bf16(a1, b1, lacc[1][1], 0,0,0);
        }
        __syncthreads();   // chunk reads done before next nt overwrites
    }
    const float invn = 1.0f / 996.0f;
    #pragma unroll
    for (int i = 0; i < 2; i++){
        #pragma unroll
        for (int j = 0; j < 2; j++){
            int e = j*16 + m16;
            #pragma unroll
            for (int reg = 0; reg < 4; reg++){
                int d = (2*w + i)*16 + quad*4 + reg;
                linkvp[(((size_t)qt*NB + b)*32 + e)*128 + d] = lacc[i][j][reg] * invn;
            }
        }
    }
}

// ---------------- quad attention + lin_out + gate + Wo + residual ----------------
// R15 structure with LDS squeezed below 160/3 KB for 3 blocks/CU (VGPR 80 -> 6
// waves/SIMD allowed; LDS was the binder at 65.5 KB). Kd stride 136->132, P
// stride 72->68 (both 2-way bank aliasing = free), LkBs aliased into the smem
// tail (disjoint from Obw; extra barrier added before the lkv staging).
#define KD_STR 132
#define P_STR  68
#define KD_BYTES (64*KD_STR*2)
#define PW_BYTES (8*32*P_STR*2)
__global__ __launch_bounds__(512, 2) void k_quad(const unsigned short* __restrict__ qk,
                                              const unsigned short* __restrict__ vT,
                                              const unsigned short* __restrict__ gateb,
                                              const float* __restrict__ linkvp,
                                              const float* __restrict__ rope,
                                              const float* __restrict__ gamma, const float* __restrict__ beta,
                                              int layer,
                                              const float* __restrict__ Wo, const float* __restrict__ bo,
                                              float* __restrict__ x){
    __shared__ __align__(16) unsigned char smem[KD_BYTES + PW_BYTES]; // 51712 B
    __shared__ float sWo[512];
    __shared__ float sbo[16];
    unsigned short* Kd = (unsigned short*)smem;
    unsigned short* Pw = (unsigned short*)(smem + KD_BYTES);
    unsigned short* LkBs = (unsigned short*)(smem + 43008); // [e][d] stride 136; disjoint from Obw [0,33792)
    int tid = threadIdx.x;
    int blk = blockIdx.x;
    int g = blk & 3, b = blk >> 2;
    int tg0 = g * GSZ;
    const float* gamL = gamma + (size_t)layer * 512;
    const float* betL = beta  + (size_t)layer * 512;
    sWo[tid] = Wo[layer*512 + tid];
    if (tid < 16) sbo[tid] = bo[layer*16 + tid];

    int w = tid >> 6, lane = tid & 63, m16 = lane & 15, quad = lane >> 4;

    // ---- derive quad_q fragments into registers (wave w owns q rows [w*32, w*32+32)) ----
    int tqA = tg0 + w*32 + m16;
    int tqB = tqA + 16;
    const unsigned short* qrowA = qk + ((size_t)b*NPAD + tqA)*128;
    const unsigned short* qrowB = qk + ((size_t)b*NPAD + tqB)*128;
    const float* rpA = rope + tqA*32 + quad*4;
    const float* rpB = rope + tqB*32 + quad*4;
    s16x8 qf[2][4];
    #pragma unroll
    for (int ks = 0; ks < 4; ks++){
        int d0 = ks*32 + quad*8;
        float4 g0 = *(const float4*)(gamL + d0), g1 = *(const float4*)(gamL + d0 + 4);
        float4 b0 = *(const float4*)(betL + d0), b1 = *(const float4*)(betL + d0 + 4);
        bool rot = (ks == 0) && (quad < 4);
        qf[0][ks] = derive_core(qrowA, d0, g0,g1,b0,b1, rpA, rot);
        qf[1][ks] = derive_core(qrowB, d0, g0,g1,b0,b1, rpB, rot);
    }

    const float* gK = gamL + 256;
    const float* bK = betL + 256;
    f32x4 oacc[2][2] = {{{0,0,0,0},{0,0,0,0}},{{0,0,0,0},{0,0,0,0}}};
    unsigned short* myP = Pw + w*32*P_STR;   // 32 rows per wave (both sub-tiles)

    for (int ch = 0; ch < 4; ch++){
        __syncthreads();   // all waves done reading Kd (prev chunk); covers sWo on ch==0
        {   // cooperative K-chunk derive: 64 tokens x 128 dims (512 threads)
            int r = tid >> 3, seg = (tid & 7) * 16;
            int tk = tg0 + ch*64 + r;
            const unsigned short* krow = qk + ((size_t)b*NPAD + tk)*128 + seg;
            unsigned int* dst = (unsigned int*)(Kd + r*KD_STR + seg);
            #pragma unroll
            for (int h = 0; h < 2; h++){
                uint4 u = ((const uint4*)krow)[h];
                unsigned int uu[4] = {u.x, u.y, u.z, u.w};
                float y[8];
                #pragma unroll
                for (int k = 0; k < 4; k++){
                    int d = h*8 + 2*k;
                    y[2*k]   = bf2f((unsigned short)(uu[k] & 0xffffu)) * gK[seg + d]     + bK[seg + d];
                    y[2*k+1] = bf2f((unsigned short)(uu[k] >> 16))     * gK[seg + d + 1] + bK[seg + d + 1];
                }
                if (seg < 32){
                    const float* rp = rope + tk*32 + (seg >> 1) + h*4;
                    #pragma unroll
                    for (int p = 0; p < 4; p++){
                        float c = rp[p], s = rp[16 + p];
                        float a = y[2*p], d = y[2*p+1];
                        y[2*p]   = a*c - d*s;
                        y[2*p+1] = d*c + a*s;
                    }
                }
                #pragma unroll
                for (int k = 0; k < 4; k++) dst[h*4 + k] = packbf(y[2*k], y[2*k+1]);
            }
        }
        __syncthreads();   // Kd ready
        // ---- S for BOTH q sub-tiles per np (kf read once, feeds 4 MFMAs) ----
        #pragma unroll
        for (int np = 0; np < 2; np++){
            f32x4 s00 = {0,0,0,0}, s01 = {0,0,0,0}, s10 = {0,0,0,0}, s11 = {0,0,0,0};
            #pragma unroll
            for (int ks = 0; ks < 4; ks++){
                s16x8 kf0 = *(const s16x8*)(Kd + ((np*2  )*16 + m16)*KD_STR + ks*32 + quad*8);
                s16x8 kf1 = *(const s16x8*)(Kd + ((np*2+1)*16 + m16)*KD_STR + ks*32 + quad*8);
                s00 = __builtin_amdgcn_mfma_f32_16x16x32_bf16(qf[0][ks], kf0, s00, 0,0,0);
                s01 = __builtin_amdgcn_mfma_f32_16x16x32_bf16(qf[0][ks], kf1, s01, 0,0,0);
                s10 = __builtin_amdgcn_mfma_f32_16x16x32_bf16(qf[1][ks], kf0, s10, 0,0,0);
                s11 = __builtin_amdgcn_mfma_f32_16x16x32_bf16(qf[1][ks], kf1, s11, 0,0,0);
            }
            #pragma unroll
            for (int j = 0; j < 2; j++){
                int kl = (np*2 + j)*16 + m16;
                bool kv = (tg0 + ch*64 + kl) < NTOK;
                #pragma unroll
                for (int reg = 0; reg < 4; reg++){
                    float a0 = fmaxf(j ? s01[reg] : s00[reg], 0.0f);
                    float a1 = fmaxf(j ? s11[reg] : s10[reg], 0.0f);
                    a0 = a0 * a0;
                    a1 = a1 * a1;
                    myP[(quad*4 + reg)*P_STR + kl]      = kv ? f2bf(a0) : (unsigned short)0;
                    myP[(16 + quad*4 + reg)*P_STR + kl] = kv ? f2bf(a1) : (unsigned short)0;
                }
            }
        }
        // ---- PV: both sub-tiles; V loaded here (short live range, L2-hot) ----
        #pragma unroll
        for (int i = 0; i < 2; i++){
            #pragma unroll
            for (int ks = 0; ks < 2; ks++){
                s16x8 pa = *(const s16x8*)(myP + (i*16 + m16)*P_STR + ks*32 + quad*8);
                s16x8 vf0 = *(const s16x8*)(vT + ((size_t)b*32 + m16)*NPAD + tg0 + ch*64 + ks*32 + quad*8);
                s16x8 vf1 = *(const s16x8*)(vT + ((size_t)b*32 + 16 + m16)*NPAD + tg0 + ch*64 + ks*32 + quad*8);
                oacc[i][0] = __builtin_amdgcn_mfma_f32_16x16x32_bf16(pa, vf0, oacc[i][0], 0,0,0);
                oacc[i][1] = __builtin_amdgcn_mfma_f32_16x16x32_bf16(pa, vf1, oacc[i][1], 0,0,0);
            }
        }
    }
    // fold the (1/256)^2 quad scale
    const float qsc = 1.0f / 65536.0f;
    #pragma unroll
    for (int i = 0; i < 2; i++)
        #pragma unroll
        for (int j = 0; j < 2; j++)
            oacc[i][j] = oacc[i][j] * qsc;
    __syncthreads();   // all P reads done: LkBs region (aliases waves 6-7 P) safe to write
    // ---- stage lin_kv B-fragments: sum 4 fp32 partials -> bf16 LDS ----
    {
        int e = tid >> 4, dbase = (tid & 15) * 8;
        float s[8];
        #pragma unroll
        for (int k = 0; k < 8; k++) s[k] = 0.f;
        #pragma unroll
        for (int part = 0; part < 4; part++){
            const float* src = linkvp + (((size_t)part*NB + b)*32 + e)*128 + dbase;
            float4 u0 = *(const float4*)src;
            float4 u1 = *(const float4*)(src + 4);
            s[0]+=u0.x; s[1]+=u0.y; s[2]+=u0.z; s[3]+=u0.w;
            s[4]+=u1.x; s[5]+=u1.y; s[6]+=u1.z; s[7]+=u1.w;
        }
        unsigned int* dst = (unsigned int*)(LkBs + e*136 + dbase);
        #pragma unroll
        for (int k = 0; k < 4; k++) dst[k] = packbf(s[2*k], s[2*k+1]);
    }
    __syncthreads();   // LkBs ready
    // ---- lin path: lin_q (in-register derive) @ LkBs ----
    {
        const float* gamQ = gamL + 128;
        const float* betQ = betL + 128;
        #pragma unroll
        for (int ks = 0; ks < 4; ks++){
            int d0 = ks*32 + quad*8;
            float4 g0 = *(const float4*)(gamQ + d0), g1 = *(const float4*)(gamQ + d0 + 4);
            float4 b0 = *(const float4*)(betQ + d0), b1 = *(const float4*)(betQ + d0 + 4);
            bool rot = (ks == 0) && (quad < 4);
            s16x8 lf0 = derive_core(qrowA, d0, g0,g1,b0,b1, rpA, rot);
            s16x8 lf1 = derive_core(qrowB, d0, g0,g1,b0,b1, rpB, rot);
            #pragma unroll
            for (int j = 0; j < 2; j++){
                s16x8 lb = *(const s16x8*)(LkBs + (j*16 + m16)*136 + ks*32 + quad*8);
                oacc[0][j] = __builtin_amdgcn_mfma_f32_16x16x32_bf16(lf0, lb, oacc[0][j], 0,0,0);
                oacc[1][j] = __builtin_amdgcn_mfma_f32_16x16x32_bf16(lf1, lb, oacc[1][j], 0,0,0);
            }
        }
    }
    // ---- stage O (per-wave slice [0,33792) of smem, disjoint from LkBs) ----
    float* Obw = (float*)smem + w*1056;  // 32 rows x stride 33 = 4224 B/wave
    #pragma unroll
    for (int i = 0; i < 2; i++)
        #pragma unroll
        for (int j = 0; j < 2; j++)
            #pragma unroll
            for (int reg = 0; reg < 4; reg++)
                Obw[(i*16 + quad*4 + reg)*33 + j*16 + m16] = oacc[i][j][reg];
    // ---- epilogue: x += (gate .* O) @ Wo + bo (per-wave rows) ----
    {
        int r = lane >> 1, dp = (lane & 1) * 8;
        int p = tg0 + w*32 + r;
        if (p < NTOK){
            const unsigned short* gr = gateb + ((size_t)b*NPAD + p)*32;
            float* xr = x + ((size_t)b * NTOK + p)*16 + dp;
            float4 x0 = *(const float4*)xr;
            float4 x1 = *(const float4*)(xr + 4);
            float a[8] = { sbo[dp]+x0.x, sbo[dp+1]+x0.y, sbo[dp+2]+x0.z, sbo[dp+3]+x0.w,
                           sbo[dp+4]+x1.x, sbo[dp+5]+x1.y, sbo[dp+6]+x1.z, sbo[dp+7]+x1.w };
            #pragma unroll
            for (int eh = 0; eh < 4; eh++){
                uint4 gu = *(const uint4*)(gr + eh*8);
                unsigned int gg[4] = {gu.x, gu.y, gu.z, gu.w};
                #pragma unroll
                for (int k = 0; k < 4; k++){
                    float gv0 = bf2f((unsigned short)(gg[k] & 0xffffu));
                    float gv1 = bf2f((unsigned short)(gg[k] >> 16));
                    int e = eh*8 + 2*k;
                    float ov0 = Obw[r*33 + e] * gv0;
                    float ov1 = Obw[r*33 + e + 1] * gv1;
                    const float* wr0 = &sWo[e*16 + dp];
                    const float* wr1 = &sWo[(e+1)*16 + dp];
                    #pragma unroll
                    for (int kk = 0; kk < 8; kk++) a[kk] += ov0 * wr0[kk] + ov1 * wr1[kk];
                }
            }
            *(float4*)xr = make_float4(a[0],a[1],a[2],a[3]);
            *(float4*)(xr+4) = make_float4(a[4],a[5],a[6],a[7]);
        }
    }
}

// ---------------- head: 256 tokens/block ----------------
__global__ __launch_bounds__(256) void k_head(const float* __restrict__ x,
                                              const float* __restrict__ Wl, const float* __restrict__ bl,
                                              const float* __restrict__ fg, float* __restrict__ h){
    __shared__ __align__(16) unsigned short WlT[512 * 40];
    __shared__ __align__(16) unsigned short As[256 * 40];
    int tid = threadIdx.x;
    int gid0 = blockIdx.x * 256;
    {
        int t = gid0 + tid;   // grid = NB*NTOK/256 exactly
        const float4* xr4 = (const float4*)(x + (size_t)t * 16);
        float cur[16]; float s2 = 0.f;
        #pragma unroll
        for (int c = 0; c < 4; c++){
            float4 v4 = xr4[c];
            cur[4*c] = v4.x; cur[4*c+1] = v4.y; cur[4*c+2] = v4.z; cur[4*c+3] = v4.w;
        }
        #pragma unroll
        for (int d = 0; d < 16; d++) s2 += cur[d]*cur[d];
        float sc = fg[0] / fmaxf(sqrtf(s2) * 0.25f, 1e-5f);
        unsigned int* dd = (unsigned int*)(As + tid * 40);
        #pragma unroll
        for (int i = 0; i < 8; i++) dd[i] = packbf(cur[2*i]*sc, cur[2*i+1]*sc);
        dd[8] = 0x00003f80u;
        #pragma unroll
        for (int i = 9; i < 16; i++) dd[i] = 0u;
    }
    int w = tid >> 6, lane = tid & 63, m16 = lane & 15, quad = lane >> 4;
    f32x4 vm[4];
    #pragma unroll
    for (int i = 0; i < 4; i++) vm[i] = (f32x4){-3e38f,-3e38f,-3e38f,-3e38f};
    for (int half = 0; half < 2; half++){
        __syncthreads();
        for (int i = tid; i < 8192; i += 256){
            int d = i >> 9, c = i & 511;
            WlT[c*40 + d] = f2bf(Wl[(size_t)d*1024 + half*512 + c]);
        }
        for (int i = tid; i < 512; i += 256){
            WlT[i*40 + 16] = f2bf(bl[half*512 + i]);
            WlT[i*40 + 17] = 0;
            unsigned int* zz = (unsigned int*)(WlT + i*40 + 18);
            #pragma unroll
            for (int k = 0; k < 7; k++) zz[k] = 0u;
        }
        __syncthreads();
        s16x8 af[4];
        #pragma unroll
        for (int i = 0; i < 4; i++)
            af[i] = *(const s16x8*)(As + (w*64 + i*16 + m16)*40 + quad*8);
        f32x4 zacc = {0,0,0,0};
        for (int nt = 0; nt < 32; nt++){
            s16x8 bf = *(const s16x8*)(WlT + (nt*16 + m16)*40 + quad*8);
            #pragma unroll
            for (int i = 0; i < 4; i++){
                f32x4 r = __builtin_amdgcn_mfma_f32_16x16x32_bf16(af[i], bf, zacc, 0,0,0);
                #pragma unroll
                for (int reg = 0; reg < 4; reg++)
                    vm[i][reg] = fmaxf(vm[i][reg], r[reg]);
            }
        }
    }
    #pragma unroll
    for (int i = 0; i < 4; i++){
        #pragma unroll
        for (int off = 1; off < 16; off <<= 1){
            #pragma unroll
            for (int reg = 0; reg < 4; reg++)
                vm[i][reg] = fmaxf(vm[i][reg], __shfl_xor(vm[i][reg], off, 64));
        }
    }
    if (m16 == 0){
        #pragma unroll
        for (int i = 0; i < 4; i++){
            int t0 = gid0 + w*64 + i*16 + quad*4;
            #pragma unroll
            for (int reg = 0; reg < 4; reg++)
                h[t0 + reg] = vm[i][reg];
        }
    }
}

// ---------------- final MLP ----------------
__global__ __launch_bounds__(256) void k_final(const float* __restrict__ h,
                                               const float* __restrict__ W1, const float* __restrict__ b1,
                                               const float* __restrict__ W2, const float* __restrict__ b2,
                                               float* __restrict__ out){
    int b = blockIdx.x;
    int tid = threadIdx.x;
    int j = tid & 31, part = tid >> 5;
    float acc = 0.f;
    for (int i = part; i < NTOK; i += 8)
        acc += h[(size_t)b*NTOK + i] * W1[(size_t)i*32 + j];
    __shared__ float red[8][33];
    red[part][j] = acc;
    __syncthreads();
    if (tid < 32){
        float s = b1[tid];
        #pragma unroll
        for (int p = 0; p < 8; p++) s += red[p][tid];
        s = fmaxf(s, 0.f);
        red[0][tid] = s * W2[tid];
    }
    __syncthreads();
    if (tid == 0){
        float s = b2[0];
        #pragma unroll
        for (int jj = 0; jj < 32; jj++) s += red[0][jj];
        out[b] = s;
    }
}

extern "C" void kernel_launch(void* const* d_in, const int* in_sizes, int n_in,
                              void* d_out, int out_size, void* d_ws, size_t ws_size,
                              hipStream_t stream){
    const int*   kmer  = (const int*)d_in[0];
    const float* emb   = (const float*)d_in[1];
    const float* ps    = (const float*)d_in[2];
    const float* ng    = (const float*)d_in[3];
    const float* Wh    = (const float*)d_in[4];
    const float* bh    = (const float*)d_in[5];
    const float* Wqk   = (const float*)d_in[6];
    const float* bqk   = (const float*)d_in[7];
    const float* gamma = (const float*)d_in[8];
    const float* beta  = (const float*)d_in[9];
    const float* Wo    = (const float*)d_in[10];
    const float* bo    = (const float*)d_in[11];
    const float* fg    = (const float*)d_in[12];
    const float* Wl    = (const float*)d_in[13];
    const float* bl    = (const float*)d_in[14];
    const float* W1    = (const float*)d_in[15];
    const float* b1    = (const float*)d_in[16];
    const float* W2    = (const float*)d_in[17];
    const float* b2    = (const float*)d_in[18];
    float* out = (float*)d_out;

    char* wsp = (char*)d_ws;
    float* x = (float*)wsp;                     wsp += (size_t)NB*NTOK*16*4;
    unsigned short* qk = (unsigned short*)wsp;  wsp += (size_t)NB*NPAD*128*2;
    unsigned short* vT = (unsigned short*)wsp;  wsp += (size_t)NB*32*NPAD*2;
    unsigned short* gateb = (unsigned short*)wsp; wsp += (size_t)NB*NPAD*32*2;
    float* linkvp = (float*)wsp;                wsp += (size_t)4*NB*32*128*4;
    float* rope = (float*)wsp;                  wsp += (size_t)NPAD*32*4;
    float* h = (float*)wsp;                     wsp += (size_t)NB*NTOK*4;

    k_embed<<<(NB*NTOK + 255)/256, 256, 0, stream>>>(kmer, emb, ps, x, rope);
    for (int layer = 0; layer < NLAY; layer++){
        k_pre<<<NB*4, 256, 0, stream>>>(x, Wh, bh, Wqk, bqk, ng, gamma, beta, rope, layer, qk, vT, gateb, linkvp);
        k_quad<<<NB*NGRP, 512, 0, stream>>>(qk, vT, gateb, linkvp, rope, gamma, beta, layer, Wo, bo, x);
    }
    k_head<<<NB*NTOK/256, 256, 0, stream>>>(x, Wl, bl, fg, h);
    k_final<<<NB, 256, 0, stream>>>(h, W1, b1, W2, b2, out);
}

// Round 18
// 804.729 us; speedup vs baseline: 1.2586x; 1.2586x over previous
//
#include <hip/hip_runtime.h>

typedef short s16x8 __attribute__((ext_vector_type(8)));
typedef float f32x4 __attribute__((ext_vector_type(4)));

#define NB    128
#define NTOK  996
#define NPAD  1024
#define NGRP  4
#define GSZ   256
#define NLAY  8

__device__ __forceinline__ float bf2f(unsigned short u){
    unsigned int v = ((unsigned int)u) << 16;
    return __uint_as_float(v);
}
__device__ __forceinline__ unsigned short f2bf(float f){
    unsigned int x = __float_as_uint(f);
    unsigned int r = (x + 0x7fffu + ((x >> 16) & 1u)) >> 16;
    return (unsigned short)r;
}
__device__ __forceinline__ unsigned int packbf(float a, float b){
    return (unsigned int)f2bf(a) | ((unsigned int)f2bf(b) << 16);
}
__device__ __forceinline__ float silu(float v){
    return v / (1.0f + __expf(-v));
}

// derive one MFMA A/B fragment (8 dims at d0) of gamma*qk+beta with rotary
__device__ __forceinline__ s16x8 derive_core(const unsigned short* __restrict__ qrow, int d0,
        float4 g0, float4 g1, float4 b0, float4 b1,
        const float* __restrict__ rp, bool rot){
    uint4 u = *(const uint4*)(qrow + d0);
    float y0 = bf2f((unsigned short)(u.x & 0xffffu))*g0.x + b0.x;
    float y1 = bf2f((unsigned short)(u.x >> 16))    *g0.y + b0.y;
    float y2 = bf2f((unsigned short)(u.y & 0xffffu))*g0.z + b0.z;
    float y3 = bf2f((unsigned short)(u.y >> 16))    *g0.w + b0.w;
    float y4 = bf2f((unsigned short)(u.z & 0xffffu))*g1.x + b1.x;
    float y5 = bf2f((unsigned short)(u.z >> 16))    *g1.y + b1.y;
    float y6 = bf2f((unsigned short)(u.w & 0xffffu))*g1.z + b1.z;
    float y7 = bf2f((unsigned short)(u.w >> 16))    *g1.w + b1.w;
    if (rot){
        float4 c4 = *(const float4*)(rp);
        float4 s4 = *(const float4*)(rp + 16);
        float a;
        a = y0; y0 = a*c4.x - y1*s4.x; y1 = y1*c4.x + a*s4.x;
        a = y2; y2 = a*c4.y - y3*s4.y; y3 = y3*c4.y + a*s4.y;
        a = y4; y4 = a*c4.z - y5*s4.z; y5 = y5*c4.z + a*s4.z;
        a = y6; y6 = a*c4.w - y7*s4.w; y7 = y7*c4.w + a*s4.w;
    }
    union { unsigned int uu[4]; s16x8 s; } r;
    r.uu[0] = packbf(y0, y1);
    r.uu[1] = packbf(y2, y3);
    r.uu[2] = packbf(y4, y5);
    r.uu[3] = packbf(y6, y7);
    return r.s;
}

// ---------------- embed + positional (+ rope table) ----------------
__global__ __launch_bounds__(256) void k_embed(const int* __restrict__ kmer,
                                               const float* __restrict__ emb,
                                               const float* __restrict__ ps,
                                               float* __restrict__ x,
                                               float* __restrict__ rope){
    int gid = blockIdx.x * 256 + threadIdx.x;
    if (gid < NPAD){
        float tf2 = (float)gid;
        #pragma unroll
        for (int i = 0; i < 16; i++){
            float inv = expf(((float)(2*i) / 32.0f) * -9.210340371976184f);
            float ang = tf2 * inv;
            rope[gid*32 + i]      = cosf(ang);
            rope[gid*32 + 16 + i] = sinf(ang);
        }
    }
    if (gid >= NB * NTOK) return;
    int b = gid / NTOK;
    int tt = gid - b * NTOK;
    int idx = kmer[gid];
    const float* er = emb + (size_t)idx * 16;
    float pscale = ps[0];
    float tf = (float)tt;
    float* xr = x + (size_t)gid * 16;
    #pragma unroll
    for (int i = 0; i < 8; i++){
        float inv = expf(((float)(2*i) / 16.0f) * -9.210340371976184f);
        float ang = tf * inv;
        xr[i]     = er[i]     + sinf(ang) * pscale;
        xr[8 + i] = er[8 + i] + cosf(ang) * pscale;
    }
}

// ---------------- per-layer tokenwise + fused lin_kv partial ----------------
// block = (b, qt): 256 padded tokens. Single-buffered chunk arena (42.5 KB LDS
// -> 3 blocks/CU).
__global__ __launch_bounds__(256, 2) void k_pre(const float* __restrict__ x,
                                             const float* __restrict__ Wh, const float* __restrict__ bh,
                                             const float* __restrict__ Wqk, const float* __restrict__ bqk,
                                             const float* __restrict__ norm_g,
                                             const float* __restrict__ gamma, const float* __restrict__ beta,
                                             const float* __restrict__ rope, int layer,
                                             unsigned short* __restrict__ qk,
                                             unsigned short* __restrict__ vT,
                                             unsigned short* __restrict__ gateb,
                                             float* __restrict__ linkvp){
    __shared__ __align__(16) unsigned short WcT[192 * 40]; // [col][dim0..15,16=bias,pad0]
    __shared__ unsigned int nrm[256][4];                   // own packed normed dims 0..7
    __shared__ __align__(16) unsigned char arena[23040];   // LkT 18432 + Vt 4608; As aliases [0,20480)
    unsigned short* As = (unsigned short*)arena;           // [token][40], dead after preload
    unsigned short* LkT = (unsigned short*)arena;
    unsigned short* Vt  = (unsigned short*)(arena + 18432);
    int tid = threadIdx.x;
    int qt = blockIdx.x & 3, b = blockIdx.x >> 2;
    const float* Whl = Wh  + (size_t)layer * 1024;
    const float* Wql = Wqk + (size_t)layer * 2048;
    const float* gLin = gamma + (size_t)layer * 512 + 384;
    const float* bLin = beta  + (size_t)layer * 512 + 384;
    for (int i = tid; i < 1024; i += 256){ int d = i >> 6, c = i & 63;  WcT[c*40 + d] = f2bf(Whl[i]); }
    for (int i = tid; i < 2048; i += 256){ int d = i >> 7, c = i & 127; WcT[(64 + c)*40 + d] = f2bf(Wql[i]); }
    if (tid < 192){
        int i = tid;
        float bv = (i < 64) ? bh[layer*64 + i] : bqk[layer*128 + (i - 64)];
        WcT[i*40 + 16] = f2bf(bv);
        WcT[i*40 + 17] = 0;
        unsigned int* zz = (unsigned int*)(WcT + i*40 + 18);
        #pragma unroll
        for (int k = 0; k < 7; k++) zz[k] = 0u;
    }
    int tt = qt*256 + tid;
    int tsafe = tt < NTOK ? tt : (NTOK - 1);
    float g = norm_g[layer];
    unsigned int* dd = (unsigned int*)(As + tid * 40);
    {
        const float4* xr4 = (const float4*)(x + ((size_t)b*NTOK + tsafe) * 16);
        float cur[16];
        float s2 = 0.f;
        #pragma unroll
        for (int c = 0; c < 4; c++){
            float4 v4 = xr4[c];
            cur[4*c] = v4.x; cur[4*c+1] = v4.y; cur[4*c+2] = v4.z; cur[4*c+3] = v4.w;
        }
        #pragma unroll
        for (int d = 0; d < 16; d++) s2 += cur[d]*cur[d];
        float sc = g / fmaxf(sqrtf(s2) * 0.25f, 1e-5f);
        #pragma unroll
        for (int i = 0; i < 4; i++) nrm[tid][i] = packbf(cur[2*i]*sc, cur[2*i+1]*sc);
        #pragma unroll
        for (int i = 0; i < 4; i++) dd[4 + i] = packbf(cur[8 + 2*i]*sc, cur[9 + 2*i]*sc);
        dd[8] = 0x00003f80u; // dim16 = 1.0 (bias lane)
        #pragma unroll
        for (int i = 9; i < 16; i++) dd[i] = 0u;
    }
    __syncthreads();
    if (tt == 0){
        #pragma unroll
        for (int i = 0; i < 4; i++) dd[i] = 0u;
    } else if (tid > 0){
        #pragma unroll
        for (int i = 0; i < 4; i++) dd[i] = nrm[tid - 1][i];
    } else {
        const float4* xp4 = (const float4*)(x + ((size_t)b*NTOK + tt - 1) * 16);
        float prv[16]; float p2 = 0.f;
        #pragma unroll
        for (int c = 0; c < 4; c++){
            float4 v4 = xp4[c];
            prv[4*c] = v4.x; prv[4*c+1] = v4.y; prv[4*c+2] = v4.z; prv[4*c+3] = v4.w;
        }
        #pragma unroll
        for (int d = 0; d < 16; d++) p2 += prv[d]*prv[d];
        float sp = g / fmaxf(sqrtf(p2) * 0.25f, 1e-5f);
        #pragma unroll
        for (int i = 0; i < 4; i++) dd[i] = packbf(prv[2*i]*sp, prv[2*i+1]*sp);
    }
    __syncthreads();
    int w = tid >> 6, lane = tid & 63, m16 = lane & 15, quad = lane >> 4;
    s16x8 wf[12];
    #pragma unroll
    for (int mi = 0; mi < 12; mi++)
        wf[mi] = *(const s16x8*)(WcT + (mi*16 + m16)*40 + quad*8);
    s16x8 bfr[4];
    #pragma unroll
    for (int nt = 0; nt < 4; nt++)
        bfr[nt] = *(const s16x8*)(As + ((w*64 + nt*16 + m16))*40 + quad*8);
    __syncthreads();   // preloads done; arena reusable
    f32x4 zacc = {0.f,0.f,0.f,0.f};
    f32x4 lacc[2][2] = {{{0,0,0,0},{0,0,0,0}},{{0,0,0,0},{0,0,0,0}}};
    #pragma unroll
    for (int nt = 0; nt < 4; nt++){
        int tloc = w*64 + nt*16 + m16;
        int ttk = qt*256 + tloc;           // within-batch token (may be pad)
        bool tv = ttk < NTOK;
        int c = w*16 + m16;                // column in chunk staging
        size_t rowq = ((size_t)b*NPAD + ttk);
        #pragma unroll
        for (int mi = 0; mi < 12; mi++){
            f32x4 r = __builtin_amdgcn_mfma_f32_16x16x32_bf16(wf[mi], bfr[nt], zacc, 0, 0, 0);
            float sv[4];
            #pragma unroll
            for (int reg = 0; reg < 4; reg++) sv[reg] = silu(r[reg]);
            int wc0 = mi*16 + quad*4;
            if (mi < 2){
                #pragma unroll
                for (int reg = 0; reg < 4; reg++){
                    unsigned short pv = tv ? f2bf(sv[reg]) : (unsigned short)0;
                    vT[((size_t)b*32 + wc0 + reg)*NPAD + ttk] = pv;
                    Vt[(wc0 + reg)*72 + c] = pv;
                }
            } else if (mi < 4){
                *(uint2*)(gateb + rowq*32 + (wc0 - 32)) = make_uint2(packbf(sv[0],sv[1]), packbf(sv[2],sv[3]));
            } else {
                int qd = wc0 - 64;
                *(uint2*)(qk + rowq*128 + qd) = make_uint2(packbf(sv[0],sv[1]), packbf(sv[2],sv[3]));
                float y0 = sv[0]*gLin[qd]   + bLin[qd];
                float y1 = sv[1]*gLin[qd+1] + bLin[qd+1];
                float y2 = sv[2]*gLin[qd+2] + bLin[qd+2];
                float y3 = sv[3]*gLin[qd+3] + bLin[qd+3];
                if (qd < 32){
                    const float* rp = rope + ttk*32 + (qd >> 1);
                    float c0 = rp[0], s0 = rp[16], c1 = rp[1], s1 = rp[17];
                    float a;
                    a = y0; y0 = a*c0 - y1*s0; y1 = y1*c0 + a*s0;
                    a = y2; y2 = a*c1 - y3*s1; y3 = y3*c1 + a*s1;
                }
                LkT[(qd+0)*72 + c] = f2bf(y0);
                LkT[(qd+1)*72 + c] = f2bf(y1);
                LkT[(qd+2)*72 + c] = f2bf(y2);
                LkT[(qd+3)*72 + c] = f2bf(y3);
            }
        }
        __syncthreads();   // LkT/Vt chunk ready
        #pragma unroll
        for (int ks2 = 0; ks2 < 2; ks2++){
            s16x8 a0 = *(const s16x8*)(LkT + ((2*w  )*16 + m16)*72 + ks2*32 + quad*8);
            s16x8 a1 = *(const s16x8*)(LkT + ((2*w+1)*16 + m16)*72 + ks2*32 + quad*8);
            s16x8 b0 = *(const s16x8*)(Vt + (m16)*72 + ks2*32 + quad*8);
            s16x8 b1 = *(const s16x8*)(Vt + (16 + m16)*72 + ks2*32 + quad*8);
            lacc[0][0] = __builtin_amdgcn_mfma_f32_16x16x32_bf16(a0, b0, lacc[0][0], 0,0,0);
            lacc[0][1] = __builtin_amdgcn_mfma_f32_16x16x32_bf16(a0, b1, lacc[0][1], 0,0,0);
            lacc[1][0] = __builtin_amdgcn_mfma_f32_16x16x32_bf16(a1, b0, lacc[1][0], 0,0,0);
            lacc[1][1] = __builtin_amdgcn_mfma_f32_16x16x32_bf16(a1, b1, lacc[1][1], 0,0,0);
        }
        __syncthreads();   // chunk reads done before next nt overwrites
    }
    const float invn = 1.0f / 996.0f;
    #pragma unroll
    for (int i = 0; i < 2; i++){
        #pragma unroll
        for (int j = 0; j < 2; j++){
            int e = j*16 + m16;
            #pragma unroll
            for (int reg = 0; reg < 4; reg++){
                int d = (2*w + i)*16 + quad*4 + reg;
                linkvp[(((size_t)qt*NB + b)*32 + e)*128 + d] = lacc[i][j][reg] * invn;
            }
        }
    }
}

// ---------------- quad attention + lin_out + gate + Wo + residual ----------------
// R15 structure (best measured 57.3us): kf read once feeds 4 MFMAs; 32-row
// per-wave P slice (stride 72 = 144 B, 16B-aligned, 2-way-bank free); Kd stride
// 136 (272 B aligned); V loaded in PV stage. launch_bounds(512,2): cap 256
// (caps<=128 provably spill ~150 MB scratch RMW). R17 lesson: LDS row strides
// must be multiples of 8 shorts or ds_read_b128 splits (132/68 regressed 55%).
#define KD_BYTES (64*136*2)
#define PW_BYTES (8*32*72*2)
__global__ __launch_bounds__(512, 2) void k_quad(const unsigned short* __restrict__ qk,
                                              const unsigned short* __restrict__ vT,
                                              const unsigned short* __restrict__ gateb,
                                              const float* __restrict__ linkvp,
                                              const float* __restrict__ rope,
                                              const float* __restrict__ gamma, const float* __restrict__ beta,
                                              int layer,
                                              const float* __restrict__ Wo, const float* __restrict__ bo,
                                              float* __restrict__ x){
    __shared__ __align__(16) unsigned char smem[KD_BYTES + PW_BYTES];
    __shared__ __align__(16) unsigned short LkBs[32 * 136]; // lin_kv B-fragments [e][d]
    __shared__ float sWo[512];
    __shared__ float sbo[16];
    unsigned short* Kd = (unsigned short*)smem;
    unsigned short* Pw = (unsigned short*)(smem + KD_BYTES);
    int tid = threadIdx.x;
    int blk = blockIdx.x;
    int g = blk & 3, b = blk >> 2;
    int tg0 = g * GSZ;
    const float* gamL = gamma + (size_t)layer * 512;
    const float* betL = beta  + (size_t)layer * 512;
    sWo[tid] = Wo[layer*512 + tid];
    if (tid < 16) sbo[tid] = bo[layer*16 + tid];

    int w = tid >> 6, lane = tid & 63, m16 = lane & 15, quad = lane >> 4;

    // ---- derive quad_q fragments into registers (wave w owns q rows [w*32, w*32+32)) ----
    int tqA = tg0 + w*32 + m16;
    int tqB = tqA + 16;
    const unsigned short* qrowA = qk + ((size_t)b*NPAD + tqA)*128;
    const unsigned short* qrowB = qk + ((size_t)b*NPAD + tqB)*128;
    const float* rpA = rope + tqA*32 + quad*4;
    const float* rpB = rope + tqB*32 + quad*4;
    s16x8 qf[2][4];
    #pragma unroll
    for (int ks = 0; ks < 4; ks++){
        int d0 = ks*32 + quad*8;
        float4 g0 = *(const float4*)(gamL + d0), g1 = *(const float4*)(gamL + d0 + 4);
        float4 b0 = *(const float4*)(betL + d0), b1 = *(const float4*)(betL + d0 + 4);
        bool rot = (ks == 0) && (quad < 4);
        qf[0][ks] = derive_core(qrowA, d0, g0,g1,b0,b1, rpA, rot);
        qf[1][ks] = derive_core(qrowB, d0, g0,g1,b0,b1, rpB, rot);
    }

    const float* gK = gamL + 256;
    const float* bK = betL + 256;
    f32x4 oacc[2][2] = {{{0,0,0,0},{0,0,0,0}},{{0,0,0,0},{0,0,0,0}}};
    unsigned short* myP = Pw + w*32*72;   // 32 rows per wave (both sub-tiles)

    for (int ch = 0; ch < 4; ch++){
        __syncthreads();   // all waves done reading Kd (prev chunk); covers sWo on ch==0
        {   // cooperative K-chunk derive: 64 tokens x 128 dims (512 threads)
            int r = tid >> 3, seg = (tid & 7) * 16;
            int tk = tg0 + ch*64 + r;
            const unsigned short* krow = qk + ((size_t)b*NPAD + tk)*128 + seg;
            unsigned int* dst = (unsigned int*)(Kd + r*136 + seg);
            #pragma unroll
            for (int h = 0; h < 2; h++){
                uint4 u = ((const uint4*)krow)[h];
                unsigned int uu[4] = {u.x, u.y, u.z, u.w};
                float y[8];
                #pragma unroll
                for (int k = 0; k < 4; k++){
                    int d = h*8 + 2*k;
                    y[2*k]   = bf2f((unsigned short)(uu[k] & 0xffffu)) * gK[seg + d]     + bK[seg + d];
                    y[2*k+1] = bf2f((unsigned short)(uu[k] >> 16))     * gK[seg + d + 1] + bK[seg + d + 1];
                }
                if (seg < 32){
                    const float* rp = rope + tk*32 + (seg >> 1) + h*4;
                    #pragma unroll
                    for (int p = 0; p < 4; p++){
                        float c = rp[p], s = rp[16 + p];
                        float a = y[2*p], d = y[2*p+1];
                        y[2*p]   = a*c - d*s;
                        y[2*p+1] = d*c + a*s;
                    }
                }
                #pragma unroll
                for (int k = 0; k < 4; k++) dst[h*4 + k] = packbf(y[2*k], y[2*k+1]);
            }
        }
        __syncthreads();   // Kd ready
        // ---- S for BOTH q sub-tiles per np (kf read once, feeds 4 MFMAs) ----
        #pragma unroll
        for (int np = 0; np < 2; np++){
            f32x4 s00 = {0,0,0,0}, s01 = {0,0,0,0}, s10 = {0,0,0,0}, s11 = {0,0,0,0};
            #pragma unroll
            for (int ks = 0; ks < 4; ks++){
                s16x8 kf0 = *(const s16x8*)(Kd + ((np*2  )*16 + m16)*136 + ks*32 + quad*8);
                s16x8 kf1 = *(const s16x8*)(Kd + ((np*2+1)*16 + m16)*136 + ks*32 + quad*8);
                s00 = __builtin_amdgcn_mfma_f32_16x16x32_bf16(qf[0][ks], kf0, s00, 0,0,0);
                s01 = __builtin_amdgcn_mfma_f32_16x16x32_bf16(qf[0][ks], kf1, s01, 0,0,0);
                s10 = __builtin_amdgcn_mfma_f32_16x16x32_bf16(qf[1][ks], kf0, s10, 0,0,0);
                s11 = __builtin_amdgcn_mfma_f32_16x16x32_bf16(qf[1][ks], kf1, s11, 0,0,0);
            }
            #pragma unroll
            for (int j = 0; j < 2; j++){
                int kl = (np*2 + j)*16 + m16;
                bool kv = (tg0 + ch*64 + kl) < NTOK;
                #pragma unroll
                for (int reg = 0; reg < 4; reg++){
                    float a0 = fmaxf(j ? s01[reg] : s00[reg], 0.0f);
                    float a1 = fmaxf(j ? s11[reg] : s10[reg], 0.0f);
                    a0 = a0 * a0;
                    a1 = a1 * a1;
                    myP[(quad*4 + reg)*72 + kl]      = kv ? f2bf(a0) : (unsigned short)0;
                    myP[(16 + quad*4 + reg)*72 + kl] = kv ? f2bf(a1) : (unsigned short)0;
                }
            }
        }
        // ---- PV: both sub-tiles; V loaded here (short live range, L2-hot) ----
        #pragma unroll
        for (int i = 0; i < 2; i++){
            #pragma unroll
            for (int ks = 0; ks < 2; ks++){
                s16x8 pa = *(const s16x8*)(myP + (i*16 + m16)*72 + ks*32 + quad*8);
                s16x8 vf0 = *(const s16x8*)(vT + ((size_t)b*32 + m16)*NPAD + tg0 + ch*64 + ks*32 + quad*8);
                s16x8 vf1 = *(const s16x8*)(vT + ((size_t)b*32 + 16 + m16)*NPAD + tg0 + ch*64 + ks*32 + quad*8);
                oacc[i][0] = __builtin_amdgcn_mfma_f32_16x16x32_bf16(pa, vf0, oacc[i][0], 0,0,0);
                oacc[i][1] = __builtin_amdgcn_mfma_f32_16x16x32_bf16(pa, vf1, oacc[i][1], 0,0,0);
            }
        }
    }
    // fold the (1/256)^2 quad scale
    const float qsc = 1.0f / 65536.0f;
    #pragma unroll
    for (int i = 0; i < 2; i++)
        #pragma unroll
        for (int j = 0; j < 2; j++)
            oacc[i][j] = oacc[i][j] * qsc;
    // ---- stage lin_kv B-fragments: sum 4 fp32 partials -> bf16 LDS ----
    {
        int e = tid >> 4, dbase = (tid & 15) * 8;
        float s[8];
        #pragma unroll
        for (int k = 0; k < 8; k++) s[k] = 0.f;
        #pragma unroll
        for (int part = 0; part < 4; part++){
            const float* src = linkvp + (((size_t)part*NB + b)*32 + e)*128 + dbase;
            float4 u0 = *(const float4*)src;
            float4 u1 = *(const float4*)(src + 4);
            s[0]+=u0.x; s[1]+=u0.y; s[2]+=u0.z; s[3]+=u0.w;
            s[4]+=u1.x; s[5]+=u1.y; s[6]+=u1.z; s[7]+=u1.w;
        }
        unsigned int* dst = (unsigned int*)(LkBs + e*136 + dbase);
        #pragma unroll
        for (int k = 0; k < 4; k++) dst[k] = packbf(s[2*k], s[2*k+1]);
    }
    __syncthreads();   // LkBs ready; all waves done with Kd/Pw (safe for O-stage reuse)
    // ---- lin path: lin_q (in-register derive) @ LkBs ----
    {
        const float* gamQ = gamL + 128;
        const float* betQ = betL + 128;
        #pragma unroll
        for (int ks = 0; ks < 4; ks++){
            int d0 = ks*32 + quad*8;
            float4 g0 = *(const float4*)(gamQ + d0), g1 = *(const float4*)(gamQ + d0 + 4);
            float4 b0 = *(const float4*)(betQ + d0), b1 = *(const float4*)(betQ + d0 + 4);
            bool rot = (ks == 0) && (quad < 4);
            s16x8 lf0 = derive_core(qrowA, d0, g0,g1,b0,b1, rpA, rot);
            s16x8 lf1 = derive_core(qrowB, d0, g0,g1,b0,b1, rpB, rot);
            #pragma unroll
            for (int j = 0; j < 2; j++){
                s16x8 lb = *(const s16x8*)(LkBs + (j*16 + m16)*136 + ks*32 + quad*8);
                oacc[0][j] = __builtin_amdgcn_mfma_f32_16x16x32_bf16(lf0, lb, oacc[0][j], 0,0,0);
                oacc[1][j] = __builtin_amdgcn_mfma_f32_16x16x32_bf16(lf1, lb, oacc[1][j], 0,0,0);
            }
        }
    }
    // ---- stage O (per-wave slice of the smem arena, as floats; within-wave only) ----
    float* Obw = (float*)smem + w*1056;  // 32 rows x stride 33 = 4224 B/wave
    #pragma unroll
    for (int i = 0; i < 2; i++)
        #pragma unroll
        for (int j = 0; j < 2; j++)
            #pragma unroll
            for (int reg = 0; reg < 4; reg++)
                Obw[(i*16 + quad*4 + reg)*33 + j*16 + m16] = oacc[i][j][reg];
    // ---- epilogue: x += (gate .* O) @ Wo + bo (per-wave rows) ----
    {
        int r = lane >> 1, dp = (lane & 1) * 8;
        int p = tg0 + w*32 + r;
        if (p < NTOK){
            const unsigned short* gr = gateb + ((size_t)b*NPAD + p)*32;
            float* xr = x + ((size_t)b * NTOK + p)*16 + dp;
            float4 x0 = *(const float4*)xr;
            float4 x1 = *(const float4*)(xr + 4);
            float a[8] = { sbo[dp]+x0.x, sbo[dp+1]+x0.y, sbo[dp+2]+x0.z, sbo[dp+3]+x0.w,
                           sbo[dp+4]+x1.x, sbo[dp+5]+x1.y, sbo[dp+6]+x1.z, sbo[dp+7]+x1.w };
            #pragma unroll
            for (int eh = 0; eh < 4; eh++){
                uint4 gu = *(const uint4*)(gr + eh*8);
                unsigned int gg[4] = {gu.x, gu.y, gu.z, gu.w};
                #pragma unroll
                for (int k = 0; k < 4; k++){
                    float gv0 = bf2f((unsigned short)(gg[k] & 0xffffu));
                    float gv1 = bf2f((unsigned short)(gg[k] >> 16));
                    int e = eh*8 + 2*k;
                    float ov0 = Obw[r*33 + e] * gv0;
                    float ov1 = Obw[r*33 + e + 1] * gv1;
                    const float* wr0 = &sWo[e*16 + dp];
                    const float* wr1 = &sWo[(e+1)*16 + dp];
                    #pragma unroll
                    for (int kk = 0; kk < 8; kk++) a[kk] += ov0 * wr0[kk] + ov1 * wr1[kk];
                }
            }
            *(float4*)xr = make_float4(a[0],a[1],a[2],a[3]);
            *(float4*)(xr+4) = make_float4(a[4],a[5],a[6],a[7]);
        }
    }
}

// ---------------- head: 256 tokens/block ----------------
__global__ __launch_bounds__(256) void k_head(const float* __restrict__ x,
                                              const float* __restrict__ Wl, const float* __restrict__ bl,
                                              const float* __restrict__ fg, float* __restrict__ h){
    __shared__ __align__(16) unsigned short WlT[512 * 40];
    __shared__ __align__(16) unsigned short As[256 * 40];
    int tid = threadIdx.x;
    int gid0 = blockIdx.x * 256;
    {
        int t = gid0 + tid;   // grid = NB*NTOK/256 exactly
        const float4* xr4 = (const float4*)(x + (size_t)t * 16);
        float cur[16]; float s2 = 0.f;
        #pragma unroll
        for (int c = 0; c < 4; c++){
            float4 v4 = xr4[c];
            cur[4*c] = v4.x; cur[4*c+1] = v4.y; cur[4*c+2] = v4.z; cur[4*c+3] = v4.w;
        }
        #pragma unroll
        for (int d = 0; d < 16; d++) s2 += cur[d]*cur[d];
        float sc = fg[0] / fmaxf(sqrtf(s2) * 0.25f, 1e-5f);
        unsigned int* dd = (unsigned int*)(As + tid * 40);
        #pragma unroll
        for (int i = 0; i < 8; i++) dd[i] = packbf(cur[2*i]*sc, cur[2*i+1]*sc);
        dd[8] = 0x00003f80u;
        #pragma unroll
        for (int i = 9; i < 16; i++) dd[i] = 0u;
    }
    int w = tid >> 6, lane = tid & 63, m16 = lane & 15, quad = lane >> 4;
    f32x4 vm[4];
    #pragma unroll
    for (int i = 0; i < 4; i++) vm[i] = (f32x4){-3e38f,-3e38f,-3e38f,-3e38f};
    for (int half = 0; half < 2; half++){
        __syncthreads();
        for (int i = tid; i < 8192; i += 256){
            int d = i >> 9, c = i & 511;
            WlT[c*40 + d] = f2bf(Wl[(size_t)d*1024 + half*512 + c]);
        }
        for (int i = tid; i < 512; i += 256){
            WlT[i*40 + 16] = f2bf(bl[half*512 + i]);
            WlT[i*40 + 17] = 0;
            unsigned int* zz = (unsigned int*)(WlT + i*40 + 18);
            #pragma unroll
            for (int k = 0; k < 7; k++) zz[k] = 0u;
        }
        __syncthreads();
        s16x8 af[4];
        #pragma unroll
        for (int i = 0; i < 4; i++)
            af[i] = *(const s16x8*)(As + (w*64 + i*16 + m16)*40 + quad*8);
        f32x4 zacc = {0,0,0,0};
        for (int nt = 0; nt < 32; nt++){
            s16x8 bf = *(const s16x8*)(WlT + (nt*16 + m16)*40 + quad*8);
            #pragma unroll
            for (int i = 0; i < 4; i++){
                f32x4 r = __builtin_amdgcn_mfma_f32_16x16x32_bf16(af[i], bf, zacc, 0,0,0);
                #pragma unroll
                for (int reg = 0; reg < 4; reg++)
                    vm[i][reg] = fmaxf(vm[i][reg], r[reg]);
            }
        }
    }
    #pragma unroll
    for (int i = 0; i < 4; i++){
        #pragma unroll
        for (int off = 1; off < 16; off <<= 1){
            #pragma unroll
            for (int reg = 0; reg < 4; reg++)
                vm[i][reg] = fmaxf(vm[i][reg], __shfl_xor(vm[i][reg], off, 64));
        }
    }
    if (m16 == 0){
        #pragma unroll
        for (int i = 0; i < 4; i++){
            int t0 = gid0 + w*64 + i*16 + quad*4;
            #pragma unroll
            for (int reg = 0; reg < 4; reg++)
                h[t0 + reg] = vm[i][reg];
        }
    }
}

// ---------------- final MLP ----------------
__global__ __launch_bounds__(256) void k_final(const float* __restrict__ h,
                                               const float* __restrict__ W1, const float* __restrict__ b1,
                                               const float* __restrict__ W2, const float* __restrict__ b2,
                                               float* __restrict__ out){
    int b = blockIdx.x;
    int tid = threadIdx.x;
    int j = tid & 31, part = tid >> 5;
    float acc = 0.f;
    for (int i = part; i < NTOK; i += 8)
        acc += h[(size_t)b*NTOK + i] * W1[(size_t)i*32 + j];
    __shared__ float red[8][33];
    red[part][j] = acc;
    __syncthreads();
    if (tid < 32){
        float s = b1[tid];
        #pragma unroll
        for (int p = 0; p < 8; p++) s += red[p][tid];
        s = fmaxf(s, 0.f);
        red[0][tid] = s * W2[tid];
    }
    __syncthreads();
    if (tid == 0){
        float s = b2[0];
        #pragma unroll
        for (int jj = 0; jj < 32; jj++) s += red[0][jj];
        out[b] = s;
    }
}

extern "C" void kernel_launch(void* const* d_in, const int* in_sizes, int n_in,
                              void* d_out, int out_size, void* d_ws, size_t ws_size,
                              hipStream_t stream){
    const int*   kmer  = (const int*)d_in[0];
    const float* emb   = (const float*)d_in[1];
    const float* ps    = (const float*)d_in[2];
    const float* ng    = (const float*)d_in[3];
    const float* Wh    = (const float*)d_in[4];
    const float* bh    = (const float*)d_in[5];
    const float* Wqk   = (const float*)d_in[6];
    const float* bqk   = (const float*)d_in[7];
    const float* gamma = (const float*)d_in[8];
    const float* beta  = (const float*)d_in[9];
    const float* Wo    = (const float*)d_in[10];
    const float* bo    = (const float*)d_in[11];
    const float* fg    = (const float*)d_in[12];
    const float* Wl    = (const float*)d_in[13];
    const float* bl    = (const float*)d_in[14];
    const float* W1    = (const float*)d_in[15];
    const float* b1    = (const float*)d_in[16];
    const float* W2    = (const float*)d_in[17];
    const float* b2    = (const float*)d_in[18];
    float* out = (float*)d_out;

    char* wsp = (char*)d_ws;
    float* x = (float*)wsp;                     wsp += (size_t)NB*NTOK*16*4;
    unsigned short* qk = (unsigned short*)wsp;  wsp += (size_t)NB*NPAD*128*2;
    unsigned short* vT = (unsigned short*)wsp;  wsp += (size_t)NB*32*NPAD*2;
    unsigned short* gateb = (unsigned short*)wsp; wsp += (size_t)NB*NPAD*32*2;
    float* linkvp = (float*)wsp;                wsp += (size_t)4*NB*32*128*4;
    float* rope = (float*)wsp;                  wsp += (size_t)NPAD*32*4;
    float* h = (float*)wsp;                     wsp += (size_t)NB*NTOK*4;

    k_embed<<<(NB*NTOK + 255)/256, 256, 0, stream>>>(kmer, emb, ps, x, rope);
    for (int layer = 0; layer < NLAY; layer++){
        k_pre<<<NB*4, 256, 0, stream>>>(x, Wh, bh, Wqk, bqk, ng, gamma, beta, rope, layer, qk, vT, gateb, linkvp);
        k_quad<<<NB*NGRP, 512, 0, stream>>>(qk, vT, gateb, linkvp, rope, gamma, beta, layer, Wo, bo, x);
    }
    k_head<<<NB*NTOK/256, 256, 0, stream>>>(x, Wl, bl, fg, h);
    k_final<<<NB, 256, 0, stream>>>(h, W1, b1, W2, b2, out);
}